// Round 5
// baseline (5807.129 us; speedup 1.0000x reference)
//
#include <hip/hip_runtime.h>
#include <hip/hip_bf16.h>
#include <math.h>

// GPT-2 block forward, fp32. B=64, T=256, C=1024, H=16, D=64, M=B*T=16384.
// Round 4: identical to rounds 2/3 (never executed — broker timeouts).
// Batch-chunked with chunk count derived from ws_size (no workspace overrun
// possible), 64KB-LDS online-softmax attention, fp32 vector-ALU GEMMs with
// fused bias/residual/GELU epilogues. ws_size is constant across calls ->
// deterministic launch sequence -> graph-capture safe.

#define C_DIM   1024
#define NHEAD   16
#define HDIM    64
#define TSEQ    256
#define BATCH   64

// ---------------------------------------------------------------------------
// LayerNorm: one block per row of 1024 floats. 256 threads * float4.
// ---------------------------------------------------------------------------
__global__ __launch_bounds__(256)
void ln_kernel(const float* __restrict__ x, const float* __restrict__ w,
               const float* __restrict__ b, float* __restrict__ out)
{
    const int row = blockIdx.x;
    const int tid = threadIdx.x;
    const float4 v = reinterpret_cast<const float4*>(x + (size_t)row * C_DIM)[tid];

    float s  = v.x + v.y + v.z + v.w;
    float ss = v.x * v.x + v.y * v.y + v.z * v.z + v.w * v.w;
    #pragma unroll
    for (int off = 32; off > 0; off >>= 1) {
        s  += __shfl_down(s, off);
        ss += __shfl_down(ss, off);
    }
    __shared__ float rs[4], rss[4];
    const int wid = tid >> 6, lane = tid & 63;
    if (lane == 0) { rs[wid] = s; rss[wid] = ss; }
    __syncthreads();
    if (tid == 0) {
        const float S  = rs[0] + rs[1] + rs[2] + rs[3];
        const float SS = rss[0] + rss[1] + rss[2] + rss[3];
        const float mu  = S * (1.0f / C_DIM);
        const float var = SS * (1.0f / C_DIM) - mu * mu;
        rs[0]  = mu;
        rss[0] = rsqrtf(var + 1e-5f);
    }
    __syncthreads();
    const float mu = rs[0], rstd = rss[0];

    const float4 wv = reinterpret_cast<const float4*>(w)[tid];
    const float4 bv = reinterpret_cast<const float4*>(b)[tid];
    float4 o;
    o.x = (v.x - mu) * rstd * wv.x + bv.x;
    o.y = (v.y - mu) * rstd * wv.y + bv.y;
    o.z = (v.z - mu) * rstd * wv.z + bv.z;
    o.w = (v.w - mu) * rstd * wv.w + bv.w;
    reinterpret_cast<float4*>(out + (size_t)row * C_DIM)[tid] = o;
}

// ---------------------------------------------------------------------------
// fp32 GEMM: C[M,N] = A[M,K] @ Bw[K,N] + bias (+res) (+GELU)
// 128x128 tile, BK=16, 256 threads, 8x8 micro-tile (4+4 split at stride 64).
// ---------------------------------------------------------------------------
template<bool GELU_ACT, bool RES>
__global__ __launch_bounds__(256, 2)
void gemm128(const float* __restrict__ A, const float* __restrict__ Bw,
             const float* __restrict__ bias, const float* __restrict__ res,
             float* __restrict__ Cout, int M, int N, int K)
{
    constexpr int BM = 128, BN = 128, BK = 16;
    __shared__ float As[BK][BM + 4];   // +4 pad: transposed stores -> 2-way (free)
    __shared__ float Bs[BK][BN];

    const int tid = threadIdx.x;
    const int tx = tid & 15;           // column group 0..15
    const int ty = tid >> 4;           // row group 0..15
    const int bm = blockIdx.x * BM;
    const int bn = blockIdx.y * BN;

    const int ar0 = tid >> 2;          // 0..63
    const int ac4 = (tid & 3) * 4;     // 0,4,8,12
    const int bk0 = tid >> 5;          // 0..7
    const int bc4 = (tid & 31) * 4;    // 0..124

    float acc[8][8];
    #pragma unroll
    for (int i = 0; i < 8; i++)
        #pragma unroll
        for (int j = 0; j < 8; j++) acc[i][j] = 0.0f;

    for (int kt = 0; kt < K; kt += BK) {
        const float4 a0 = *reinterpret_cast<const float4*>(A + (size_t)(bm + ar0) * K + kt + ac4);
        const float4 a1 = *reinterpret_cast<const float4*>(A + (size_t)(bm + 64 + ar0) * K + kt + ac4);
        const float4 b0 = *reinterpret_cast<const float4*>(Bw + (size_t)(kt + bk0) * N + bn + bc4);
        const float4 b1 = *reinterpret_cast<const float4*>(Bw + (size_t)(kt + 8 + bk0) * N + bn + bc4);

        __syncthreads();
        As[ac4 + 0][ar0] = a0.x; As[ac4 + 1][ar0] = a0.y;
        As[ac4 + 2][ar0] = a0.z; As[ac4 + 3][ar0] = a0.w;
        As[ac4 + 0][64 + ar0] = a1.x; As[ac4 + 1][64 + ar0] = a1.y;
        As[ac4 + 2][64 + ar0] = a1.z; As[ac4 + 3][64 + ar0] = a1.w;
        *reinterpret_cast<float4*>(&Bs[bk0][bc4])     = b0;
        *reinterpret_cast<float4*>(&Bs[bk0 + 8][bc4]) = b1;
        __syncthreads();

        #pragma unroll
        for (int kk = 0; kk < BK; kk++) {
            const float4 av0 = *reinterpret_cast<const float4*>(&As[kk][ty * 4]);
            const float4 av1 = *reinterpret_cast<const float4*>(&As[kk][64 + ty * 4]);
            const float4 bv0 = *reinterpret_cast<const float4*>(&Bs[kk][tx * 4]);
            const float4 bv1 = *reinterpret_cast<const float4*>(&Bs[kk][64 + tx * 4]);
            const float a[8] = {av0.x, av0.y, av0.z, av0.w, av1.x, av1.y, av1.z, av1.w};
            const float bb[8] = {bv0.x, bv0.y, bv0.z, bv0.w, bv1.x, bv1.y, bv1.z, bv1.w};
            #pragma unroll
            for (int i = 0; i < 8; i++)
                #pragma unroll
                for (int j = 0; j < 8; j++)
                    acc[i][j] += a[i] * bb[j];
        }
    }

    #pragma unroll
    for (int i = 0; i < 8; i++) {
        const int r = bm + ((i < 4) ? (ty * 4 + i) : (64 + ty * 4 + (i - 4)));
        #pragma unroll
        for (int j = 0; j < 8; j++) {
            const int c = bn + ((j < 4) ? (tx * 4 + j) : (64 + tx * 4 + (j - 4)));
            float v = acc[i][j] + bias[c];
            if (RES)      v += res[(size_t)r * N + c];
            if (GELU_ACT) v = 0.5f * v * (1.0f + erff(v * 0.70710678118654752f));
            Cout[(size_t)r * N + c] = v;
        }
    }
}

// ---------------------------------------------------------------------------
// Causal attention, one block per (b_local, h) within a chunk.
// K/V tiled 128 rows at a time (64 KB LDS). Thread t owns query row t;
// online softmax carries across tiles. k index is wave-uniform -> LDS
// reads are broadcasts (conflict-free).
// qkv chunk layout: [rows, 3072]; q at h*64, k at 1024+h*64, v at 2048+h*64.
// y chunk layout: [rows, 1024].
// ---------------------------------------------------------------------------
#define KTILE 128
__global__ __launch_bounds__(256)
void attn_kernel(const float* __restrict__ qkv, float* __restrict__ y)
{
    __shared__ float Ks[KTILE][HDIM];
    __shared__ float Vs[KTILE][HDIM];

    const int bl = blockIdx.x >> 4;    // local batch index within chunk
    const int h  = blockIdx.x & 15;
    const size_t base = (size_t)bl * TSEQ * 3072 + (size_t)h * HDIM;

    const int t = threadIdx.x;
    float q[HDIM];
    const float* qp = qkv + base + (size_t)t * 3072;
    #pragma unroll
    for (int i = 0; i < 16; i++) {
        const float4 v4 = *reinterpret_cast<const float4*>(qp + i * 4);
        q[i * 4 + 0] = v4.x; q[i * 4 + 1] = v4.y; q[i * 4 + 2] = v4.z; q[i * 4 + 3] = v4.w;
    }

    float acc[HDIM];
    #pragma unroll
    for (int d = 0; d < HDIM; d++) acc[d] = 0.0f;
    float m = -INFINITY, l = 0.0f;
    const float scale = 0.125f;  // 1/sqrt(64)

    for (int ts = 0; ts < TSEQ; ts += KTILE) {
        __syncthreads();           // previous tile's compute done before overwrite
        for (int idx = threadIdx.x; idx < KTILE * 16; idx += 256) {
            const int row = idx >> 4;
            const int c4  = (idx & 15) * 4;
            const size_t p = base + (size_t)(ts + row) * 3072 + c4;
            *reinterpret_cast<float4*>(&Ks[row][c4]) = *reinterpret_cast<const float4*>(qkv + p + 1024);
            *reinterpret_cast<float4*>(&Vs[row][c4]) = *reinterpret_cast<const float4*>(qkv + p + 2048);
        }
        __syncthreads();

        const int ke = (t < ts + KTILE ? t : ts + KTILE - 1);
        for (int k = ts; k <= ke; k++) {
            const int kr = k - ts;
            float s = 0.0f;
            #pragma unroll
            for (int d = 0; d < HDIM; d++) s += q[d] * Ks[kr][d];
            s *= scale;
            const float mn = fmaxf(m, s);
            const float cold = __expf(m - mn);
            const float p    = __expf(s - mn);
            l = l * cold + p;
            #pragma unroll
            for (int d = 0; d < HDIM; d++) acc[d] = acc[d] * cold + p * Vs[kr][d];
            m = mn;
        }
    }

    const float inv = 1.0f / l;
    float* yp = y + ((size_t)(bl * TSEQ + t)) * C_DIM + (size_t)h * HDIM;
    #pragma unroll
    for (int i = 0; i < 16; i++) {
        float4 o;
        o.x = acc[i * 4 + 0] * inv; o.y = acc[i * 4 + 1] * inv;
        o.z = acc[i * 4 + 2] * inv; o.w = acc[i * 4 + 3] * inv;
        *reinterpret_cast<float4*>(yp + i * 4) = o;
    }
}

// ---------------------------------------------------------------------------
extern "C" void kernel_launch(void* const* d_in, const int* in_sizes, int n_in,
                              void* d_out, int out_size, void* d_ws, size_t ws_size,
                              hipStream_t stream)
{
    const float* x      = (const float*)d_in[0];
    const float* ln1_w  = (const float*)d_in[1];
    const float* ln1_b  = (const float*)d_in[2];
    const float* w_attn = (const float*)d_in[3];
    const float* b_attn = (const float*)d_in[4];
    const float* w_proj = (const float*)d_in[5];
    const float* b_proj = (const float*)d_in[6];
    const float* ln2_w  = (const float*)d_in[7];
    const float* ln2_b  = (const float*)d_in[8];
    const float* w_fc   = (const float*)d_in[9];
    const float* b_fc   = (const float*)d_in[10];
    const float* w_out  = (const float*)d_in[11];
    const float* b_out  = (const float*)d_in[12];
    float* out = (float*)d_out;

    // Both phases need exactly rows*5120 floats of workspace:
    //   attn phase: hbuf[rows*1024] | qkv[rows*3072] | ybuf[rows*1024]
    //   mlp  phase: hbuf[rows*1024] | act[rows*4096]   (act aliases qkv)
    // Pick the fewest chunks whose footprint fits ws_size (deterministic in
    // ws_size -> identical work every call -> graph-capture safe).
    int nchunk = 64;
    for (int cand = 4; cand <= 64; cand *= 2) {
        const size_t rows = (size_t)(BATCH / cand) * TSEQ;
        if (rows * 5120 * sizeof(float) <= ws_size) { nchunk = cand; break; }
    }
    const int bchunk = BATCH / nchunk;
    const int rows   = bchunk * TSEQ;

    float* hbuf = (float*)d_ws;
    float* qkv  = hbuf + (size_t)rows * C_DIM;
    float* ybuf = qkv  + (size_t)rows * 3072;
    float* act  = qkv;  // MLP reuses qkv region (rows*4096 <= rows*(3072+1024))

    // --- attention branch, per chunk ---
    for (int c = 0; c < nchunk; c++) {
        const size_t r0 = (size_t)c * rows;
        const float* xc = x   + r0 * C_DIM;
        float*      oc  = out + r0 * C_DIM;
        ln_kernel<<<rows, 256, 0, stream>>>(xc, ln1_w, ln1_b, hbuf);
        gemm128<false, false><<<dim3(rows / 128, 3072 / 128), 256, 0, stream>>>(
            hbuf, w_attn, b_attn, nullptr, qkv, rows, 3072, 1024);
        attn_kernel<<<bchunk * NHEAD, 256, 0, stream>>>(qkv, ybuf);
        gemm128<false, true><<<dim3(rows / 128, 1024 / 128), 256, 0, stream>>>(
            ybuf, w_proj, b_proj, xc, oc, rows, 1024, 1024);
    }

    // --- MLP branch, per chunk ---
    for (int c = 0; c < nchunk; c++) {
        const size_t r0 = (size_t)c * rows;
        float* oc = out + r0 * C_DIM;
        ln_kernel<<<rows, 256, 0, stream>>>(oc, ln2_w, ln2_b, hbuf);
        gemm128<true, false><<<dim3(rows / 128, 4096 / 128), 256, 0, stream>>>(
            hbuf, w_fc, b_fc, nullptr, act, rows, 4096, 1024);
        gemm128<false, true><<<dim3(rows / 128, 1024 / 128), 256, 0, stream>>>(
            act, w_out, b_out, oc, oc, rows, 1024, 4096);
    }
}

// Round 7
// 1104.379 us; speedup vs baseline: 5.2583x; 5.2583x over previous
//
#include <hip/hip_runtime.h>
#include <math.h>

// GPT-2 block forward. B=64, T=256, C=1024, H=16, D=64, M=16384.
// Round 7 = round 6 resubmitted (never executed - broker timeouts).
// bf16-MFMA GEMMs (16x16x32), fp32 accumulate/epilogues.
// Weights pre-transposed+converted to bf16 Wt[N][K] once per launch (NT GEMM).
// Activations flow as bf16 between GEMMs; attention computes fp32 from bf16 qkv.
// LDS chunk-position XOR swizzle (pos = kgrp ^ ((row>>1)&3)) keeps b128
// reads/writes spread across all 8 LDS bank-classes.

#define C_DIM   1024
#define NHEAD   16
#define HDIM    64
#define TSEQ    256
#define BATCH   64
#define KTILE   128

typedef __attribute__((ext_vector_type(4))) float fx4;
typedef __attribute__((ext_vector_type(8))) short sx8;

__device__ __forceinline__ ushort f2bf(float f) {
    uint x = __float_as_uint(f);
    x += 0x7fffu + ((x >> 16) & 1u);          // round-to-nearest-even
    return (ushort)(x >> 16);
}
__device__ __forceinline__ float bf2f(ushort u) {
    return __uint_as_float(((uint)u) << 16);
}

// ---------------------------------------------------------------------------
// Weight convert+transpose: W[K][N] fp32 -> Wt[N][K] bf16. 64x64 tiles.
// ---------------------------------------------------------------------------
__global__ __launch_bounds__(256)
void wconv(const float* __restrict__ W, ushort* __restrict__ Wt, int K, int N)
{
    __shared__ float T[64][65];
    const int kt = blockIdx.x << 6, nt = blockIdx.y << 6;
    const int ln = threadIdx.x & 63, g4 = threadIdx.x >> 6;
    #pragma unroll
    for (int i = 0; i < 16; ++i) {
        const int r = i * 4 + g4;
        T[r][ln] = W[(size_t)(kt + r) * N + nt + ln];
    }
    __syncthreads();
    #pragma unroll
    for (int i = 0; i < 16; ++i) {
        const int r = i * 4 + g4;
        Wt[(size_t)(nt + r) * K + kt + ln] = f2bf(T[ln][r]);
    }
}

// ---------------------------------------------------------------------------
// LayerNorm fp32 in -> bf16 out. One block per 1024-float row.
// ---------------------------------------------------------------------------
__global__ __launch_bounds__(256)
void ln_bf16(const float* __restrict__ x, const float* __restrict__ w,
             const float* __restrict__ b, ushort* __restrict__ out)
{
    const int row = blockIdx.x;
    const int tid = threadIdx.x;
    const float4 v = reinterpret_cast<const float4*>(x + (size_t)row * C_DIM)[tid];

    float s  = v.x + v.y + v.z + v.w;
    float ss = v.x * v.x + v.y * v.y + v.z * v.z + v.w * v.w;
    #pragma unroll
    for (int off = 32; off > 0; off >>= 1) {
        s  += __shfl_down(s, off);
        ss += __shfl_down(ss, off);
    }
    __shared__ float rs[4], rss[4];
    const int wid = tid >> 6, lane = tid & 63;
    if (lane == 0) { rs[wid] = s; rss[wid] = ss; }
    __syncthreads();
    if (tid == 0) {
        const float S  = rs[0] + rs[1] + rs[2] + rs[3];
        const float SS = rss[0] + rss[1] + rss[2] + rss[3];
        const float mu  = S * (1.0f / C_DIM);
        const float var = SS * (1.0f / C_DIM) - mu * mu;
        rs[0]  = mu;
        rss[0] = rsqrtf(var + 1e-5f);
    }
    __syncthreads();
    const float mu = rs[0], rstd = rss[0];

    const float4 wv = reinterpret_cast<const float4*>(w)[tid];
    const float4 bv = reinterpret_cast<const float4*>(b)[tid];
    ushort4 o;
    o.x = f2bf((v.x - mu) * rstd * wv.x + bv.x);
    o.y = f2bf((v.y - mu) * rstd * wv.y + bv.y);
    o.z = f2bf((v.z - mu) * rstd * wv.z + bv.z);
    o.w = f2bf((v.w - mu) * rstd * wv.w + bv.w);
    reinterpret_cast<ushort4*>(out + (size_t)row * C_DIM)[tid] = o;
}

// ---------------------------------------------------------------------------
// bf16 MFMA GEMM (NT): C[M,N] = A[M,K] * Wt[N,K]^T + bias (+res) (+gelu)
// 128x128 tile, BK=32, 256 threads (4 waves, 2x2), 64x64 per wave.
// EPI: 0 = bf16 out + bias; 1 = fp32 out + bias + res; 2 = bf16 out + bias + gelu
// LDS layout: [row][chunk] where chunk position = kgrp ^ ((row>>1)&3).
// Any k-bijection shared by A- and B-fragments yields a correct contraction.
// ---------------------------------------------------------------------------
template<int EPI>
__global__ __launch_bounds__(256)
void gemm_mfma(const ushort* __restrict__ A, const ushort* __restrict__ Wt,
               const float* __restrict__ bias, const float* __restrict__ res,
               void* __restrict__ outv, int M, int N, int K)
{
    __shared__ ushort As[128 * 32];
    __shared__ ushort Bs[128 * 32];

    const int tid  = threadIdx.x;
    const int lane = tid & 63;
    const int wid  = tid >> 6;
    const int wr   = (wid >> 1) << 6;      // wave row offset: 0 / 64
    const int wc   = (wid & 1) << 6;       // wave col offset: 0 / 64
    const int bm = blockIdx.x << 7;
    const int bn = blockIdx.y << 7;

    // staging: thread t covers LDS chunks (row = t>>2, pos = t&3) and row+64
    const int srow = tid >> 2;             // 0..63
    const int spos = tid & 3;
    const int skg  = spos ^ ((srow >> 1) & 3);   // source k-group (same at row+64)
    const size_t ga0 = (size_t)(bm + srow)      * K + skg * 8;
    const size_t ga1 = (size_t)(bm + srow + 64) * K + skg * 8;
    const size_t gb0 = (size_t)(bn + srow)      * K + skg * 8;
    const size_t gb1 = (size_t)(bn + srow + 64) * K + skg * 8;
    ushort* la0 = &As[srow * 32 + spos * 8];
    ushort* la1 = &As[(srow + 64) * 32 + spos * 8];
    ushort* lb0 = &Bs[srow * 32 + spos * 8];
    ushort* lb1 = &Bs[(srow + 64) * 32 + spos * 8];

    // fragment read offsets: lane supplies row (lane&15), k-group (lane>>4)
    const int frow = lane & 15;
    const int fpos = ((lane >> 4) ^ ((frow >> 1) & 3)) * 8;
    int aoff[4], boff[4];
    #pragma unroll
    for (int i = 0; i < 4; ++i) {
        aoff[i] = (wr + i * 16 + frow) * 32 + fpos;
        boff[i] = (wc + i * 16 + frow) * 32 + fpos;
    }

    fx4 acc[4][4] = {};

    const int nk = K >> 5;
    sx8 ra0 = *(const sx8*)(A  + ga0);
    sx8 ra1 = *(const sx8*)(A  + ga1);
    sx8 rb0 = *(const sx8*)(Wt + gb0);
    sx8 rb1 = *(const sx8*)(Wt + gb1);

    for (int t = 0; t < nk; ++t) {
        __syncthreads();                     // LDS free (prev compute done)
        *(sx8*)la0 = ra0; *(sx8*)la1 = ra1;
        *(sx8*)lb0 = rb0; *(sx8*)lb1 = rb1;
        __syncthreads();                     // LDS visible
        if (t + 1 < nk) {                    // prefetch overlaps compute
            const int ko = (t + 1) << 5;
            ra0 = *(const sx8*)(A  + ga0 + ko);
            ra1 = *(const sx8*)(A  + ga1 + ko);
            rb0 = *(const sx8*)(Wt + gb0 + ko);
            rb1 = *(const sx8*)(Wt + gb1 + ko);
        }
        sx8 af[4], bf[4];
        #pragma unroll
        for (int i = 0; i < 4; ++i) af[i] = *(const sx8*)&As[aoff[i]];
        #pragma unroll
        for (int i = 0; i < 4; ++i) bf[i] = *(const sx8*)&Bs[boff[i]];
        #pragma unroll
        for (int i = 0; i < 4; ++i)
            #pragma unroll
            for (int j = 0; j < 4; ++j)
                acc[i][j] = __builtin_amdgcn_mfma_f32_16x16x32_bf16(
                    af[i], bf[j], acc[i][j], 0, 0, 0);
    }

    // epilogue: D row = (lane>>4)*4 + reg, col = lane&15  [HW-verified m89/m91]
    const int r0 = bm + wr + (lane >> 4) * 4;
    const int c0 = bn + wc + (lane & 15);
    #pragma unroll
    for (int i = 0; i < 4; ++i) {
        #pragma unroll
        for (int r = 0; r < 4; ++r) {
            const int row = r0 + i * 16 + r;
            #pragma unroll
            for (int j = 0; j < 4; ++j) {
                const int col = c0 + j * 16;
                float v = acc[i][j][r] + bias[col];
                if (EPI == 1) {
                    v += res[(size_t)row * N + col];
                    ((float*)outv)[(size_t)row * N + col] = v;
                } else if (EPI == 2) {
                    v = 0.5f * v * (1.0f + erff(v * 0.70710678118654752f));
                    ((ushort*)outv)[(size_t)row * N + col] = f2bf(v);
                } else {
                    ((ushort*)outv)[(size_t)row * N + col] = f2bf(v);
                }
            }
        }
    }
}

// ---------------------------------------------------------------------------
// Causal attention from bf16 qkv, fp32 compute, bf16 out.
// One block per (b_local, h); K/V tiles of 128 rows in LDS (64 KB fp32).
// ---------------------------------------------------------------------------
__global__ __launch_bounds__(256)
void attn_kernel(const ushort* __restrict__ qkv, ushort* __restrict__ y)
{
    __shared__ float Ks[KTILE][HDIM];
    __shared__ float Vs[KTILE][HDIM];

    const int bl = blockIdx.x >> 4;
    const int h  = blockIdx.x & 15;
    const size_t base = (size_t)bl * TSEQ * 3072 + (size_t)h * HDIM;

    const int t = threadIdx.x;
    float q[HDIM];
    const ushort* qp = qkv + base + (size_t)t * 3072;
    #pragma unroll
    for (int i = 0; i < 8; ++i) {
        sx8 v8 = *(const sx8*)(qp + i * 8);
        #pragma unroll
        for (int j = 0; j < 8; ++j) q[i * 8 + j] = bf2f((ushort)v8[j]);
    }

    float acc[HDIM];
    #pragma unroll
    for (int d = 0; d < HDIM; ++d) acc[d] = 0.0f;
    float m = -INFINITY, l = 0.0f;
    const float scale = 0.125f;

    for (int ts = 0; ts < TSEQ; ts += KTILE) {
        __syncthreads();
        for (int idx = threadIdx.x; idx < KTILE * 8; idx += 256) {
            const int row = idx >> 3;
            const int c8  = (idx & 7) * 8;
            const ushort* p = qkv + base + (size_t)(ts + row) * 3072 + c8;
            sx8 kv = *(const sx8*)(p + 1024);
            sx8 vv = *(const sx8*)(p + 2048);
            #pragma unroll
            for (int j = 0; j < 8; ++j) {
                Ks[row][c8 + j] = bf2f((ushort)kv[j]);
                Vs[row][c8 + j] = bf2f((ushort)vv[j]);
            }
        }
        __syncthreads();

        const int ke = (t < ts + KTILE ? t : ts + KTILE - 1);
        for (int k = ts; k <= ke; ++k) {
            const int kr = k - ts;
            float s = 0.0f;
            #pragma unroll
            for (int d = 0; d < HDIM; ++d) s += q[d] * Ks[kr][d];
            s *= scale;
            const float mn = fmaxf(m, s);
            const float cold = __expf(m - mn);
            const float p    = __expf(s - mn);
            l = l * cold + p;
            #pragma unroll
            for (int d = 0; d < HDIM; ++d) acc[d] = acc[d] * cold + p * Vs[kr][d];
            m = mn;
        }
    }

    const float inv = 1.0f / l;
    ushort* yp = y + ((size_t)(bl * TSEQ + t)) * C_DIM + (size_t)h * HDIM;
    #pragma unroll
    for (int i = 0; i < 16; ++i) {
        ushort4 o;
        o.x = f2bf(acc[i * 4 + 0] * inv);
        o.y = f2bf(acc[i * 4 + 1] * inv);
        o.z = f2bf(acc[i * 4 + 2] * inv);
        o.w = f2bf(acc[i * 4 + 3] * inv);
        reinterpret_cast<ushort4*>(yp)[i] = o;
    }
}

// ---------------------------------------------------------------------------
extern "C" void kernel_launch(void* const* d_in, const int* in_sizes, int n_in,
                              void* d_out, int out_size, void* d_ws, size_t ws_size,
                              hipStream_t stream)
{
    const float* x      = (const float*)d_in[0];
    const float* ln1_w  = (const float*)d_in[1];
    const float* ln1_b  = (const float*)d_in[2];
    const float* w_attn = (const float*)d_in[3];
    const float* b_attn = (const float*)d_in[4];
    const float* w_proj = (const float*)d_in[5];
    const float* b_proj = (const float*)d_in[6];
    const float* ln2_w  = (const float*)d_in[7];
    const float* ln2_b  = (const float*)d_in[8];
    const float* w_fc   = (const float*)d_in[9];
    const float* b_fc   = (const float*)d_in[10];
    const float* w_out  = (const float*)d_in[11];
    const float* b_out  = (const float*)d_in[12];
    float* out = (float*)d_out;

    // Workspace: [wt 24MiB bf16 weights][hbuf][qkvb][ybuf] (act aliases qkvb+ybuf)
    // per-chunk bytes = rows * (2048 + 6144 + 2048) = rows*10240.
    ushort* wbf     = (ushort*)d_ws;
    ushort* wt_attn = wbf;                 // 1024*3072
    ushort* wt_proj = wbf + 3145728;       // 1024*1024
    ushort* wt_fc   = wbf + 4194304;       // 1024*4096
    ushort* wt_out  = wbf + 8388608;       // 4096*1024
    const size_t wbytes = 12582912ull * 2;

    int nchunk = 64;
    for (int cand = 1; cand <= 64; cand *= 2) {
        const size_t rows = (size_t)(BATCH / cand) * TSEQ;
        if (wbytes + rows * 10240ull <= ws_size) { nchunk = cand; break; }
    }
    const int bchunk = BATCH / nchunk;
    const int rows   = bchunk * TSEQ;

    ushort* hbuf = wbf + 12582912;
    ushort* qkvb = hbuf + (size_t)rows * 1024;
    ushort* ybuf = qkvb + (size_t)rows * 3072;
    ushort* act  = qkvb;                   // rows*4096 spans qkvb+ybuf exactly

    // weights -> bf16, transposed to [N][K]
    wconv<<<dim3(16, 48), 256, 0, stream>>>(w_attn, wt_attn, 1024, 3072);
    wconv<<<dim3(16, 16), 256, 0, stream>>>(w_proj, wt_proj, 1024, 1024);
    wconv<<<dim3(16, 64), 256, 0, stream>>>(w_fc,   wt_fc,   1024, 4096);
    wconv<<<dim3(64, 16), 256, 0, stream>>>(w_out,  wt_out,  4096, 1024);

    // --- attention branch ---
    for (int c = 0; c < nchunk; ++c) {
        const size_t r0 = (size_t)c * rows;
        const float* xc = x   + r0 * C_DIM;
        float*       oc = out + r0 * C_DIM;
        ln_bf16<<<rows, 256, 0, stream>>>(xc, ln1_w, ln1_b, hbuf);
        gemm_mfma<0><<<dim3(rows / 128, 3072 / 128), 256, 0, stream>>>(
            hbuf, wt_attn, b_attn, nullptr, qkvb, rows, 3072, 1024);
        attn_kernel<<<bchunk * NHEAD, 256, 0, stream>>>(qkvb, ybuf);
        gemm_mfma<1><<<dim3(rows / 128, 1024 / 128), 256, 0, stream>>>(
            ybuf, wt_proj, b_proj, xc, oc, rows, 1024, 1024);
    }

    // --- MLP branch ---
    for (int c = 0; c < nchunk; ++c) {
        const size_t r0 = (size_t)c * rows;
        float* oc = out + r0 * C_DIM;
        ln_bf16<<<rows, 256, 0, stream>>>(oc, ln2_w, ln2_b, hbuf);
        gemm_mfma<2><<<dim3(rows / 128, 4096 / 128), 256, 0, stream>>>(
            hbuf, wt_fc, b_fc, nullptr, act, rows, 4096, 1024);
        gemm_mfma<1><<<dim3(rows / 128, 1024 / 128), 256, 0, stream>>>(
            act, wt_out, b_out, oc, oc, rows, 1024, 4096);
    }
}

// Round 8
// 907.508 us; speedup vs baseline: 6.3990x; 1.2169x over previous
//
#include <hip/hip_runtime.h>
#include <math.h>

// GPT-2 block forward. B=64, T=256, C=1024, H=16, D=64, M=16384.
// Round 8: attention rewritten as 4-wave MFMA flash kernel (QK^T and PV on
// matrix cores, online softmax in C-fragment layout, P via per-wave LDS
// transpose, V transposed at stage time). GEMMs unchanged from round 7
// (bf16 MFMA 128x128, passed at absmax=0.03125).

#define C_DIM   1024
#define NHEAD   16
#define HDIM    64
#define TSEQ    256
#define BATCH   64

typedef __attribute__((ext_vector_type(4))) float fx4;
typedef __attribute__((ext_vector_type(8))) short sx8;

__device__ __forceinline__ ushort f2bf(float f) {
    uint x = __float_as_uint(f);
    x += 0x7fffu + ((x >> 16) & 1u);          // round-to-nearest-even
    return (ushort)(x >> 16);
}
__device__ __forceinline__ float bf2f(ushort u) {
    return __uint_as_float(((uint)u) << 16);
}

// ---------------------------------------------------------------------------
// Weight convert+transpose: W[K][N] fp32 -> Wt[N][K] bf16. 64x64 tiles.
// ---------------------------------------------------------------------------
__global__ __launch_bounds__(256)
void wconv(const float* __restrict__ W, ushort* __restrict__ Wt, int K, int N)
{
    __shared__ float T[64][65];
    const int kt = blockIdx.x << 6, nt = blockIdx.y << 6;
    const int ln = threadIdx.x & 63, g4 = threadIdx.x >> 6;
    #pragma unroll
    for (int i = 0; i < 16; ++i) {
        const int r = i * 4 + g4;
        T[r][ln] = W[(size_t)(kt + r) * N + nt + ln];
    }
    __syncthreads();
    #pragma unroll
    for (int i = 0; i < 16; ++i) {
        const int r = i * 4 + g4;
        Wt[(size_t)(nt + r) * K + kt + ln] = f2bf(T[ln][r]);
    }
}

// ---------------------------------------------------------------------------
// LayerNorm fp32 in -> bf16 out. One block per 1024-float row.
// ---------------------------------------------------------------------------
__global__ __launch_bounds__(256)
void ln_bf16(const float* __restrict__ x, const float* __restrict__ w,
             const float* __restrict__ b, ushort* __restrict__ out)
{
    const int row = blockIdx.x;
    const int tid = threadIdx.x;
    const float4 v = reinterpret_cast<const float4*>(x + (size_t)row * C_DIM)[tid];

    float s  = v.x + v.y + v.z + v.w;
    float ss = v.x * v.x + v.y * v.y + v.z * v.z + v.w * v.w;
    #pragma unroll
    for (int off = 32; off > 0; off >>= 1) {
        s  += __shfl_down(s, off);
        ss += __shfl_down(ss, off);
    }
    __shared__ float rs[4], rss[4];
    const int wid = tid >> 6, lane = tid & 63;
    if (lane == 0) { rs[wid] = s; rss[wid] = ss; }
    __syncthreads();
    if (tid == 0) {
        const float S  = rs[0] + rs[1] + rs[2] + rs[3];
        const float SS = rss[0] + rss[1] + rss[2] + rss[3];
        const float mu  = S * (1.0f / C_DIM);
        const float var = SS * (1.0f / C_DIM) - mu * mu;
        rs[0]  = mu;
        rss[0] = rsqrtf(var + 1e-5f);
    }
    __syncthreads();
    const float mu = rs[0], rstd = rss[0];

    const float4 wv = reinterpret_cast<const float4*>(w)[tid];
    const float4 bv = reinterpret_cast<const float4*>(b)[tid];
    ushort4 o;
    o.x = f2bf((v.x - mu) * rstd * wv.x + bv.x);
    o.y = f2bf((v.y - mu) * rstd * wv.y + bv.y);
    o.z = f2bf((v.z - mu) * rstd * wv.z + bv.z);
    o.w = f2bf((v.w - mu) * rstd * wv.w + bv.w);
    reinterpret_cast<ushort4*>(out + (size_t)row * C_DIM)[tid] = o;
}

// ---------------------------------------------------------------------------
// bf16 MFMA GEMM (NT): C[M,N] = A[M,K] * Wt[N,K]^T + bias (+res) (+gelu)
// 128x128 tile, BK=32, 256 threads (4 waves, 2x2), 64x64 per wave.
// EPI: 0 = bf16 out + bias; 1 = fp32 out + bias + res; 2 = bf16 out + bias + gelu
// ---------------------------------------------------------------------------
template<int EPI>
__global__ __launch_bounds__(256)
void gemm_mfma(const ushort* __restrict__ A, const ushort* __restrict__ Wt,
               const float* __restrict__ bias, const float* __restrict__ res,
               void* __restrict__ outv, int M, int N, int K)
{
    __shared__ ushort As[128 * 32];
    __shared__ ushort Bs[128 * 32];

    const int tid  = threadIdx.x;
    const int lane = tid & 63;
    const int wid  = tid >> 6;
    const int wr   = (wid >> 1) << 6;
    const int wc   = (wid & 1) << 6;
    const int bm = blockIdx.x << 7;
    const int bn = blockIdx.y << 7;

    const int srow = tid >> 2;
    const int spos = tid & 3;
    const int skg  = spos ^ ((srow >> 1) & 3);
    const size_t ga0 = (size_t)(bm + srow)      * K + skg * 8;
    const size_t ga1 = (size_t)(bm + srow + 64) * K + skg * 8;
    const size_t gb0 = (size_t)(bn + srow)      * K + skg * 8;
    const size_t gb1 = (size_t)(bn + srow + 64) * K + skg * 8;
    ushort* la0 = &As[srow * 32 + spos * 8];
    ushort* la1 = &As[(srow + 64) * 32 + spos * 8];
    ushort* lb0 = &Bs[srow * 32 + spos * 8];
    ushort* lb1 = &Bs[(srow + 64) * 32 + spos * 8];

    const int frow = lane & 15;
    const int fpos = ((lane >> 4) ^ ((frow >> 1) & 3)) * 8;
    int aoff[4], boff[4];
    #pragma unroll
    for (int i = 0; i < 4; ++i) {
        aoff[i] = (wr + i * 16 + frow) * 32 + fpos;
        boff[i] = (wc + i * 16 + frow) * 32 + fpos;
    }

    fx4 acc[4][4] = {};

    const int nk = K >> 5;
    sx8 ra0 = *(const sx8*)(A  + ga0);
    sx8 ra1 = *(const sx8*)(A  + ga1);
    sx8 rb0 = *(const sx8*)(Wt + gb0);
    sx8 rb1 = *(const sx8*)(Wt + gb1);

    for (int t = 0; t < nk; ++t) {
        __syncthreads();
        *(sx8*)la0 = ra0; *(sx8*)la1 = ra1;
        *(sx8*)lb0 = rb0; *(sx8*)lb1 = rb1;
        __syncthreads();
        if (t + 1 < nk) {
            const int ko = (t + 1) << 5;
            ra0 = *(const sx8*)(A  + ga0 + ko);
            ra1 = *(const sx8*)(A  + ga1 + ko);
            rb0 = *(const sx8*)(Wt + gb0 + ko);
            rb1 = *(const sx8*)(Wt + gb1 + ko);
        }
        sx8 af[4], bf[4];
        #pragma unroll
        for (int i = 0; i < 4; ++i) af[i] = *(const sx8*)&As[aoff[i]];
        #pragma unroll
        for (int i = 0; i < 4; ++i) bf[i] = *(const sx8*)&Bs[boff[i]];
        #pragma unroll
        for (int i = 0; i < 4; ++i)
            #pragma unroll
            for (int j = 0; j < 4; ++j)
                acc[i][j] = __builtin_amdgcn_mfma_f32_16x16x32_bf16(
                    af[i], bf[j], acc[i][j], 0, 0, 0);
    }

    const int r0 = bm + wr + (lane >> 4) * 4;
    const int c0 = bn + wc + (lane & 15);
    #pragma unroll
    for (int i = 0; i < 4; ++i) {
        #pragma unroll
        for (int r = 0; r < 4; ++r) {
            const int row = r0 + i * 16 + r;
            #pragma unroll
            for (int j = 0; j < 4; ++j) {
                const int col = c0 + j * 16;
                float v = acc[i][j][r] + bias[col];
                if (EPI == 1) {
                    v += res[(size_t)row * N + col];
                    ((float*)outv)[(size_t)row * N + col] = v;
                } else if (EPI == 2) {
                    v = 0.5f * v * (1.0f + erff(v * 0.70710678118654752f));
                    ((ushort*)outv)[(size_t)row * N + col] = f2bf(v);
                } else {
                    ((ushort*)outv)[(size_t)row * N + col] = f2bf(v);
                }
            }
        }
    }
}

// ---------------------------------------------------------------------------
// MFMA flash attention. One block per (b_local, h); 4 waves; wave w owns
// q-rows [64w, 64w+64) and iterates kv-tiles 0..w (causal).
// Ks[kv][72]: K rows, padded stride (b128 reads hit banks 4r%32, 2-way max).
// Vt[d][264]: V transposed at stage (PV B-frags need contiguous kv at fixed d).
// Pl[wave][64][72]: per-wave P tile, C-layout write -> A-frag read (wave-
// private, no barrier; compiler inserts lgkmcnt).
// ---------------------------------------------------------------------------
__global__ __launch_bounds__(256, 1)
void attn_mfma(const ushort* __restrict__ qkv, ushort* __restrict__ y)
{
    __shared__ ushort Ks[256 * 72];      // 36864 B
    __shared__ ushort Vt[64 * 264];      // 33792 B
    __shared__ ushort Pl[4][64 * 72];    // 36864 B  (total 107520 B)

    const int bl = blockIdx.x >> 4;
    const int h  = blockIdx.x & 15;
    const size_t base = (size_t)bl * TSEQ * 3072 + (size_t)h * HDIM;

    const int tid  = threadIdx.x;
    const int lane = tid & 63;
    const int w    = tid >> 6;
    const int c15  = lane & 15;
    const int grp  = lane >> 4;

    // ---- stage K rows + transposed V (one kv row per thread) ----
    {
        const int kv = tid;
        const ushort* kp = qkv + base + (size_t)kv * 3072 + 1024;
        const ushort* vp = qkv + base + (size_t)kv * 3072 + 2048;
        #pragma unroll
        for (int j = 0; j < 8; ++j) {
            sx8 k8 = *(const sx8*)(kp + j * 8);
            *(sx8*)&Ks[kv * 72 + j * 8] = k8;
            sx8 v8 = *(const sx8*)(vp + j * 8);
            #pragma unroll
            for (int e = 0; e < 8; ++e)
                Vt[(j * 8 + e) * 264 + kv] = (ushort)v8[e];
        }
    }

    // ---- Q fragments: wave's 64 rows x 64 d as 4 m-tiles x 2 k-chunks ----
    sx8 aq[4][2];
    #pragma unroll
    for (int m = 0; m < 4; ++m)
        #pragma unroll
        for (int kc = 0; kc < 2; ++kc) {
            const int qr = w * 64 + m * 16 + c15;
            aq[m][kc] = *(const sx8*)(qkv + base + (size_t)qr * 3072 + kc * 32 + grp * 8);
        }

    __syncthreads();

    fx4 oacc[4][4] = {};                 // [m][dn]
    float m_s[4][4], l_s[4][4];          // [m][r], replicated across 16-lane group
    #pragma unroll
    for (int m = 0; m < 4; ++m)
        #pragma unroll
        for (int r = 0; r < 4; ++r) { m_s[m][r] = -INFINITY; l_s[m][r] = 0.0f; }

    for (int t = 0; t <= w; ++t) {
        const int kt = t * 64;
        const bool diag = (t == w);

        // ---- S = Q K^T (NT pattern, same as verified gemm_mfma) ----
        fx4 s[4][4] = {};                // [m][n]
        #pragma unroll
        for (int kc = 0; kc < 2; ++kc)
            #pragma unroll
            for (int n = 0; n < 4; ++n) {
                sx8 bk = *(const sx8*)&Ks[(kt + n * 16 + c15) * 72 + kc * 32 + grp * 8];
                #pragma unroll
                for (int m = 0; m < 4; ++m)
                    s[m][n] = __builtin_amdgcn_mfma_f32_16x16x32_bf16(
                        aq[m][kc], bk, s[m][n], 0, 0, 0);
            }

        // ---- scale + causal mask on diagonal tile ----
        #pragma unroll
        for (int m = 0; m < 4; ++m)
            #pragma unroll
            for (int n = 0; n < 4; ++n)
                #pragma unroll
                for (int r = 0; r < 4; ++r) {
                    float v = s[m][n][r] * 0.125f;
                    if (diag && (n * 16 + c15) > (m * 16 + grp * 4 + r)) v = -1e30f;
                    s[m][n][r] = v;
                }

        // ---- online softmax (row = (grp*4+r) within m-tile) ----
        #pragma unroll
        for (int m = 0; m < 4; ++m)
            #pragma unroll
            for (int r = 0; r < 4; ++r) {
                float mx = fmaxf(fmaxf(s[m][0][r], s[m][1][r]),
                                 fmaxf(s[m][2][r], s[m][3][r]));
                #pragma unroll
                for (int off = 1; off < 16; off <<= 1)
                    mx = fmaxf(mx, __shfl_xor(mx, off));
                const float mnew = fmaxf(m_s[m][r], mx);
                const float cold = __expf(m_s[m][r] - mnew);
                m_s[m][r] = mnew;
                float rsum = 0.0f;
                #pragma unroll
                for (int n = 0; n < 4; ++n) {
                    const float p = __expf(s[m][n][r] - mnew);
                    s[m][n][r] = p;
                    rsum += p;
                }
                #pragma unroll
                for (int off = 1; off < 16; off <<= 1)
                    rsum += __shfl_xor(rsum, off);
                l_s[m][r] = l_s[m][r] * cold + rsum;
                #pragma unroll
                for (int dn = 0; dn < 4; ++dn)
                    oacc[m][dn][r] *= cold;
            }

        // ---- P (C-layout) -> bf16 -> wave-private LDS ----
        #pragma unroll
        for (int m = 0; m < 4; ++m)
            #pragma unroll
            for (int n = 0; n < 4; ++n)
                #pragma unroll
                for (int r = 0; r < 4; ++r)
                    Pl[w][(m * 16 + grp * 4 + r) * 72 + n * 16 + c15] =
                        f2bf(s[m][n][r]);

        // ---- O += P V (A-frags from Pl, B-frags from Vt) ----
        #pragma unroll
        for (int kc = 0; kc < 2; ++kc) {
            sx8 ap[4];
            #pragma unroll
            for (int m = 0; m < 4; ++m)
                ap[m] = *(const sx8*)&Pl[w][(m * 16 + c15) * 72 + kc * 32 + grp * 8];
            #pragma unroll
            for (int dn = 0; dn < 4; ++dn) {
                sx8 bv = *(const sx8*)&Vt[(dn * 16 + c15) * 264 + kt + kc * 32 + grp * 8];
                #pragma unroll
                for (int m = 0; m < 4; ++m)
                    oacc[m][dn] = __builtin_amdgcn_mfma_f32_16x16x32_bf16(
                        ap[m], bv, oacc[m][dn], 0, 0, 0);
            }
        }
    }

    // ---- epilogue: O / l -> y bf16 ----
    #pragma unroll
    for (int m = 0; m < 4; ++m)
        #pragma unroll
        for (int r = 0; r < 4; ++r) {
            const float inv = 1.0f / l_s[m][r];
            const int row = bl * TSEQ + w * 64 + m * 16 + grp * 4 + r;
            ushort* yp = y + (size_t)row * C_DIM + h * HDIM;
            #pragma unroll
            for (int dn = 0; dn < 4; ++dn)
                yp[dn * 16 + c15] = f2bf(oacc[m][dn][r] * inv);
        }
}

// ---------------------------------------------------------------------------
extern "C" void kernel_launch(void* const* d_in, const int* in_sizes, int n_in,
                              void* d_out, int out_size, void* d_ws, size_t ws_size,
                              hipStream_t stream)
{
    const float* x      = (const float*)d_in[0];
    const float* ln1_w  = (const float*)d_in[1];
    const float* ln1_b  = (const float*)d_in[2];
    const float* w_attn = (const float*)d_in[3];
    const float* b_attn = (const float*)d_in[4];
    const float* w_proj = (const float*)d_in[5];
    const float* b_proj = (const float*)d_in[6];
    const float* ln2_w  = (const float*)d_in[7];
    const float* ln2_b  = (const float*)d_in[8];
    const float* w_fc   = (const float*)d_in[9];
    const float* b_fc   = (const float*)d_in[10];
    const float* w_out  = (const float*)d_in[11];
    const float* b_out  = (const float*)d_in[12];
    float* out = (float*)d_out;

    ushort* wbf     = (ushort*)d_ws;
    ushort* wt_attn = wbf;                 // 1024*3072
    ushort* wt_proj = wbf + 3145728;       // 1024*1024
    ushort* wt_fc   = wbf + 4194304;       // 1024*4096
    ushort* wt_out  = wbf + 8388608;       // 4096*1024
    const size_t wbytes = 12582912ull * 2;

    int nchunk = 64;
    for (int cand = 1; cand <= 64; cand *= 2) {
        const size_t rows = (size_t)(BATCH / cand) * TSEQ;
        if (wbytes + rows * 10240ull <= ws_size) { nchunk = cand; break; }
    }
    const int bchunk = BATCH / nchunk;
    const int rows   = bchunk * TSEQ;

    ushort* hbuf = wbf + 12582912;
    ushort* qkvb = hbuf + (size_t)rows * 1024;
    ushort* ybuf = qkvb + (size_t)rows * 3072;
    ushort* act  = qkvb;                   // rows*4096 spans qkvb+ybuf

    wconv<<<dim3(16, 48), 256, 0, stream>>>(w_attn, wt_attn, 1024, 3072);
    wconv<<<dim3(16, 16), 256, 0, stream>>>(w_proj, wt_proj, 1024, 1024);
    wconv<<<dim3(16, 64), 256, 0, stream>>>(w_fc,   wt_fc,   1024, 4096);
    wconv<<<dim3(64, 16), 256, 0, stream>>>(w_out,  wt_out,  4096, 1024);

    for (int c = 0; c < nchunk; ++c) {
        const size_t r0 = (size_t)c * rows;
        const float* xc = x   + r0 * C_DIM;
        float*       oc = out + r0 * C_DIM;
        ln_bf16<<<rows, 256, 0, stream>>>(xc, ln1_w, ln1_b, hbuf);
        gemm_mfma<0><<<dim3(rows / 128, 3072 / 128), 256, 0, stream>>>(
            hbuf, wt_attn, b_attn, nullptr, qkvb, rows, 3072, 1024);
        attn_mfma<<<bchunk * NHEAD, 256, 0, stream>>>(qkvb, ybuf);
        gemm_mfma<1><<<dim3(rows / 128, 1024 / 128), 256, 0, stream>>>(
            ybuf, wt_proj, b_proj, xc, oc, rows, 1024, 1024);
    }

    for (int c = 0; c < nchunk; ++c) {
        const size_t r0 = (size_t)c * rows;
        float* oc = out + r0 * C_DIM;
        ln_bf16<<<rows, 256, 0, stream>>>(oc, ln2_w, ln2_b, hbuf);
        gemm_mfma<2><<<dim3(rows / 128, 4096 / 128), 256, 0, stream>>>(
            hbuf, wt_fc, b_fc, nullptr, act, rows, 4096, 1024);
        gemm_mfma<1><<<dim3(rows / 128, 1024 / 128), 256, 0, stream>>>(
            act, wt_out, b_out, oc, oc, rows, 1024, 4096);
    }
}